// Round 9
// baseline (153.801 us; speedup 1.0000x reference)
//
#include <hip/hip_runtime.h>
#include <hip/hip_bf16.h>
#include <math.h>

#define BB 4
#define TT 4096
#define DD 1024
#define HH 64
#define MTOT (BB * TT)   // 16384 rows
#define NCH 4            // key chunks per q row-block (1024 keys each)

typedef short short8 __attribute__((ext_vector_type(8)));
typedef float f32x4  __attribute__((ext_vector_type(4)));
typedef unsigned int u32;
typedef unsigned long long u64;

__device__ __forceinline__ unsigned short f2bf(float f) {
    unsigned u = __builtin_bit_cast(unsigned, f);
    unsigned r = (u + 0x7fffu + ((u >> 16) & 1u)) >> 16;
    return (unsigned short)r;
}

__device__ __forceinline__ unsigned long long pack4(float a, float b, float c, float d) {
    return (unsigned long long)f2bf(a) |
           ((unsigned long long)f2bf(b) << 16) |
           ((unsigned long long)f2bf(c) << 32) |
           ((unsigned long long)f2bf(d) << 48);
}

// async global->LDS DMA, 16B/lane; lds dest = wave-uniform base + lane*16
__device__ __forceinline__ void gl16(const void* g, void* l) {
    __builtin_amdgcn_global_load_lds(
        (const __attribute__((address_space(1))) u32*)g,
        (__attribute__((address_space(3))) u32*)l, 16, 0, 0);
}

// Workspace layout — byte-identical to prior passing rounds
#define QOFF  0
#define KOFF  (MTOT * HH)
#define VOFF  (2 * MTOT * HH)
#define BF_TOTAL (3 * MTOT * HH)

// ---------------------------------------------------------------------------
// Kernel 0: transpose W (1024x64 fp32) -> Wt (64x1024 bf16), 3 matrices.
// (proven, verbatim)
// ---------------------------------------------------------------------------
__global__ __launch_bounds__(256) void transpose_w(
    const float* __restrict__ Wq, const float* __restrict__ Wk,
    const float* __restrict__ Wv, unsigned short* __restrict__ Wt)
{
    const int w = blockIdx.y;
    const float* W = (w == 0) ? Wq : (w == 1) ? Wk : Wv;
    unsigned short* o = Wt + (size_t)w * 64 * 1024;
    const int t  = threadIdx.x;
    const int n4 = t & 15;
    const int k0 = blockIdx.x * 64 + (t >> 4) * 4;

    float v[4][4];
#pragma unroll
    for (int ii = 0; ii < 4; ++ii) {
        float4 r = *(const float4*)&W[(size_t)(k0 + ii) * HH + n4 * 4];
        v[ii][0] = r.x; v[ii][1] = r.y; v[ii][2] = r.z; v[ii][3] = r.w;
    }
#pragma unroll
    for (int cc = 0; cc < 4; ++cc) {
        unsigned long long pk = pack4(v[0][cc], v[1][cc], v[2][cc], v[3][cc]);
        *(unsigned long long*)&o[(size_t)(n4 * 4 + cc) * 1024 + k0] = pk;
    }
}

// ---------------------------------------------------------------------------
// Kernel 1: fused QKV projection (proven DMA K-loop, verbatim R6/R8).
// Q pre-scaled by SC*log2(e); A-fragment pack via v_cvt_pk_bf16_f32.
// ---------------------------------------------------------------------------
__global__ __launch_bounds__(256, 2) void qkv_proj(
    const float* __restrict__ x,
    const unsigned short* __restrict__ Wt,
    unsigned short* __restrict__ qkv)
{
    const int tid   = threadIdx.x;
    const int lane  = tid & 63;
    const int wave  = tid >> 6;      // 0..3
    const int l15   = lane & 15;
    const int quad  = lane >> 4;
    const int m0    = blockIdx.x * 32;
    const int strip = wave & 1;
    const int half  = wave >> 1;

    __shared__ float          Af[2][32 * 64];    // [row][k] fp32, raw (DMA)
    __shared__ unsigned short Bs[2][192 * 64];   // [col][k] bf16, raw (DMA)

    const int ar  = lane >> 4;             // A: row within 4-row instr group
    const int as  = lane & 15;             // A: dest 16B chunk
    const int bc  = lane >> 3;             // B: col within 8-col instr group
    const int bs2 = (lane & 7) ^ bc;       // B: swizzled source chunk

#define STAGEW(it, p)                                                        \
    {                                                                        \
        const int kc_ = (it) * 64;                                           \
        _Pragma("unroll")                                                    \
        for (int jj = 0; jj < 2; ++jj) {                                     \
            int j   = wave * 2 + jj;                                         \
            int row = 4 * j + ar;                                            \
            int sw  = as ^ (row & 15);                                       \
            gl16(x + (size_t)(m0 + row) * DD + kc_ + sw * 4,                 \
                 &Af[p][j * 256]);                                           \
        }                                                                    \
        _Pragma("unroll")                                                    \
        for (int jj = 0; jj < 6; ++jj) {                                     \
            int j    = wave * 6 + jj;                                        \
            int gcol = 8 * j + bc;                                           \
            gl16(Wt + (size_t)gcol * 1024 + kc_ + bs2 * 8,                   \
                 &Bs[p][j * 512]);                                           \
        }                                                                    \
    }

    f32x4 acc[6];
#pragma unroll
    for (int i = 0; i < 6; ++i) acc[i] = (f32x4){0.f, 0.f, 0.f, 0.f};

    STAGEW(0, 0)
    __syncthreads();
    int p = 0;

    for (int it = 0; it < 16; ++it) {
        if (it < 15) STAGEW(it + 1, p ^ 1)

        const int row = strip * 16 + l15;
#pragma unroll
        for (int ks = 0; ks < 2; ++ks) {
            int c0 = ks * 8 + quad * 2;
            float4 a0 = *(const float4*)&Af[p][row * 64 + ((c0)     ^ l15) * 4];
            float4 a1 = *(const float4*)&Af[p][row * 64 + ((c0 + 1) ^ l15) * 4];
            short8 af;
            {
                u32* ap = (u32*)&af;
                asm("v_cvt_pk_bf16_f32 %0, %1, %2" : "=v"(ap[0]) : "v"(a0.x), "v"(a0.y));
                asm("v_cvt_pk_bf16_f32 %0, %1, %2" : "=v"(ap[1]) : "v"(a0.z), "v"(a0.w));
                asm("v_cvt_pk_bf16_f32 %0, %1, %2" : "=v"(ap[2]) : "v"(a1.x), "v"(a1.y));
                asm("v_cvt_pk_bf16_f32 %0, %1, %2" : "=v"(ap[3]) : "v"(a1.z), "v"(a1.w));
            }
            int cb = (ks * 4 + quad) ^ (l15 & 7);
#pragma unroll
            for (int jj = 0; jj < 6; ++jj) {
                int col = (half * 6 + jj) * 16 + l15;
                short8 bfr = *(const short8*)&Bs[p][col * 64 + cb * 8];
                acc[jj] = __builtin_amdgcn_mfma_f32_16x16x32_bf16(af, bfr, acc[jj], 0, 0, 0);
            }
        }
        __syncthreads();
        p ^= 1;
    }
#undef STAGEW

    // ---- epilogue: q (pre-scaled) / k as [b t h] bf16, v transposed [b h t]
    const float QS = 0.125f * 1.44269504088896f;   // scale * log2(e)
    unsigned short* q_bf  = qkv + QOFF;
    unsigned short* k_bf  = qkv + KOFF;
    unsigned short* vt_bf = qkv + VOFF;
#pragma unroll
    for (int jj = 0; jj < 6; ++jj) {
        int g = half * 6 + jj, w = g >> 2, col = (g & 3) * 16 + l15;
#pragma unroll
        for (int r = 0; r < 4; ++r) {
            int m = m0 + strip * 16 + quad * 4 + r;
            float val = acc[jj][r];
            if (w == 0) val *= QS;
            unsigned short bv = f2bf(val);
            if (w == 0)      q_bf[(size_t)m * HH + col] = bv;
            else if (w == 1) k_bf[(size_t)m * HH + col] = bv;
            else {
                int b = m >> 12, t = m & 4095;
                vt_bf[(size_t)b * HH * TT + (size_t)col * TT + t] = bv;
            }
        }
    }
}

// ---------------------------------------------------------------------------
// Kernel 2: causal flash attention — R8's proven structure with two exact
// grafts:
//  * deferred l-reduction: per-round ssum stays per-lane (m_run — and hence
//    every alpha — is identical across the 4 lanes of an l15-group, so
//    partial sums scale uniformly); ONE cross-lane reduce in the epilogue.
//    Removes 2 shfl_xor + dependent add from every round's serial chain.
//  * nc==1 fast path: qt<16 blocks are their row-block's only chunk ->
//    normalize in-register and write fp32 `out` directly, skipping the
//    Opart/Mpart/Lpart round-trip.  combine shrinks to qt>=16.
// Everything else verbatim R8 (= R6 best, 152.6 µs total).
// ---------------------------------------------------------------------------
__global__ __launch_bounds__(256, 3) void flash_attn(
    const unsigned short* __restrict__ qkv,
    float* __restrict__ Opart,
    float* __restrict__ Mpart,
    float* __restrict__ Lpart,
    float* __restrict__ out)
{
    const int qt = 63 - blockIdx.x;   // heavy blocks dispatch first
    const int b  = blockIdx.y;
    const int c  = blockIdx.z;
    if (c * 16 > qt) return;
    const int j0   = c * 16;
    const int jmax = min(j0 + 16, qt + 1);

    const int tid  = threadIdx.x;
    const int lane = tid & 63;
    const int wave = tid >> 6;
    const int l15  = lane & 15;
    const int quad = lane >> 4;

    const unsigned short* q_g  = qkv + QOFF + (size_t)b * TT * HH;
    const unsigned short* k_g  = qkv + KOFF + (size_t)b * TT * HH;
    const unsigned short* vt_g = qkv + VOFF + (size_t)b * HH * TT;

    __shared__ unsigned short Ks[2][128 * 64];   // dbuf K, [key][h], src-swizzled
    __shared__ unsigned short Vs[64 * 128];      // single V^T, [h][key], src-swizzled

    // DMA lane decomposition (constant per thread)
    const int kr3 = lane >> 3;        // K: row within 8-row group
    const int kch = lane & 7;         // K: dest 16B chunk
    const int vr2 = lane >> 4;        // V: row within 4-row group
    const int vch = lane & 15;        // V: dest 16B chunk

#define STAGE_K(jr_, p_)                                                      \
    {                                                                         \
        const unsigned short* kp = k_g + (size_t)(jr_) * 64 * HH;             \
        _Pragma("unroll")                                                     \
        for (int i = 0; i < 4; ++i) {                                         \
            int g = wave * 4 + i;                                             \
            gl16(kp + (size_t)(g * 8 + kr3) * HH + (kch ^ kr3) * 8,           \
                 &Ks[p_][g * 512]);                                           \
        }                                                                     \
    }
#define STAGE_V(jr_)                                                          \
    {                                                                         \
        const unsigned short* vp = vt_g + (size_t)(jr_) * 64;                 \
        _Pragma("unroll")                                                     \
        for (int i = 0; i < 4; ++i) {                                         \
            int g = wave * 4 + i;                                             \
            int h = g * 4 + vr2;                                              \
            gl16(vp + (size_t)h * TT + (vch ^ ((h >> 1) & 7)) * 8,            \
                 &Vs[g * 512]);                                               \
        }                                                                     \
    }

    short8 qf[2];
#pragma unroll
    for (int kk = 0; kk < 2; ++kk)
        qf[kk] = *(const short8*)&q_g[(size_t)(qt * 64 + wave * 16 + l15) * HH + kk * 32 + quad * 8];

    f32x4 ov[4];
#pragma unroll
    for (int i = 0; i < 4; ++i) ov[i] = (f32x4){0.f, 0.f, 0.f, 0.f};
    float m_run = -1e30f, l_run = 0.f;   // l_run: per-lane partial (deferred)

    STAGE_K(j0, 0)
    __syncthreads();   // drains prologue K DMA
    int p = 0;

    const int swv = 2 * ((l15 >> 1) & 7);   // V read-side swizzle (even XOR)

    for (int jr = j0; jr < jmax; jr += 2) {
        const bool two = (jmax - jr) >= 2;

        STAGE_V(jr)                               // drained at barrier B

        // ---- QK^T both tiles (S^T: MFMA rows=key, col(l15)=q)
        f32x4 st0[4], st1[4];
#pragma unroll
        for (int i = 0; i < 4; ++i) {
            st0[i] = (f32x4){0.f, 0.f, 0.f, 0.f};
            st1[i] = (f32x4){0.f, 0.f, 0.f, 0.f};
        }
        __builtin_amdgcn_s_setprio(1);
#pragma unroll
        for (int kk = 0; kk < 2; ++kk)
#pragma unroll
            for (int mt = 0; mt < 4; ++mt) {
                short8 a = *(const short8*)&Ks[p][(mt * 16 + l15) * 64 +
                                                  (((kk * 4 + quad) ^ (l15 & 7)) * 8)];
                st0[mt] = __builtin_amdgcn_mfma_f32_16x16x32_bf16(a, qf[kk], st0[mt], 0, 0, 0);
            }
        if (two) {
#pragma unroll
            for (int kk = 0; kk < 2; ++kk)
#pragma unroll
                for (int mt = 0; mt < 4; ++mt) {
                    short8 a = *(const short8*)&Ks[p][(64 + mt * 16 + l15) * 64 +
                                                      (((kk * 4 + quad) ^ (l15 & 7)) * 8)];
                    st1[mt] = __builtin_amdgcn_mfma_f32_16x16x32_bf16(a, qf[kk], st1[mt], 0, 0, 0);
                }
        }
        __builtin_amdgcn_s_setprio(0);

        // ---- causal mask on the diagonal tile (scores pre-scaled)
        const int qg = wave * 16 + l15;
        if (jr == qt) {
#pragma unroll
            for (int mt = 0; mt < 4; ++mt)
#pragma unroll
                for (int r = 0; r < 4; ++r)
                    if (mt * 16 + quad * 4 + r > qg) st0[mt][r] = -1e30f;
        } else if (two && jr + 1 == qt) {
#pragma unroll
            for (int mt = 0; mt < 4; ++mt)
#pragma unroll
                for (int r = 0; r < 4; ++r)
                    if (mt * 16 + quad * 4 + r > qg) st1[mt][r] = -1e30f;
        }

        // ---- ONE softmax over the whole 128-key round
        float mloc = -1e30f;
#pragma unroll
        for (int mt = 0; mt < 4; ++mt)
#pragma unroll
            for (int r = 0; r < 4; ++r) mloc = fmaxf(mloc, st0[mt][r]);
        if (two) {
#pragma unroll
            for (int mt = 0; mt < 4; ++mt)
#pragma unroll
                for (int r = 0; r < 4; ++r) mloc = fmaxf(mloc, st1[mt][r]);
        }
        mloc = fmaxf(mloc, __shfl_xor(mloc, 16));
        mloc = fmaxf(mloc, __shfl_xor(mloc, 32));

        // exact defer-rescale: when no q-row's max grew, alpha==1 identically
        if (!__all(mloc <= m_run)) {
            const float m_new = fmaxf(m_run, mloc);
            const float alpha = exp2f(m_run - m_new);
            m_run = m_new;
            l_run *= alpha;      // per-lane partial; alpha uniform per l15-group
            float a0 = __shfl(alpha, quad * 4 + 0);
            float a1 = __shfl(alpha, quad * 4 + 1);
            float a2 = __shfl(alpha, quad * 4 + 2);
            float a3 = __shfl(alpha, quad * 4 + 3);
#pragma unroll
            for (int ht = 0; ht < 4; ++ht) {
                ov[ht][0] *= a0; ov[ht][1] *= a1;
                ov[ht][2] *= a2; ov[ht][3] *= a3;
            }
        }

        float ssum = 0.f;
#pragma unroll
        for (int mt = 0; mt < 4; ++mt)
#pragma unroll
            for (int r = 0; r < 4; ++r) {
                float pv = exp2f(st0[mt][r] - m_run);
                st0[mt][r] = pv; ssum += pv;
            }
        if (two) {
#pragma unroll
            for (int mt = 0; mt < 4; ++mt)
#pragma unroll
                for (int r = 0; r < 4; ++r) {
                    float pv = exp2f(st1[mt][r] - m_run);
                    st1[mt][r] = pv; ssum += pv;
                }
        }
        l_run += ssum;           // deferred: no cross-lane reduce per round

        // ---- build permuted-k A-fragments in registers (no LDS, no shuffle)
        short8 pa00, pa01, pa10, pa11;
        {
            u32* pp = (u32*)&pa00;
            asm("v_cvt_pk_bf16_f32 %0, %1, %2" : "=v"(pp[0]) : "v"(st0[0][0]), "v"(st0[0][1]));
            asm("v_cvt_pk_bf16_f32 %0, %1, %2" : "=v"(pp[1]) : "v"(st0[0][2]), "v"(st0[0][3]));
            asm("v_cvt_pk_bf16_f32 %0, %1, %2" : "=v"(pp[2]) : "v"(st0[1][0]), "v"(st0[1][1]));
            asm("v_cvt_pk_bf16_f32 %0, %1, %2" : "=v"(pp[3]) : "v"(st0[1][2]), "v"(st0[1][3]));
            pp = (u32*)&pa01;
            asm("v_cvt_pk_bf16_f32 %0, %1, %2" : "=v"(pp[0]) : "v"(st0[2][0]), "v"(st0[2][1]));
            asm("v_cvt_pk_bf16_f32 %0, %1, %2" : "=v"(pp[1]) : "v"(st0[2][2]), "v"(st0[2][3]));
            asm("v_cvt_pk_bf16_f32 %0, %1, %2" : "=v"(pp[2]) : "v"(st0[3][0]), "v"(st0[3][1]));
            asm("v_cvt_pk_bf16_f32 %0, %1, %2" : "=v"(pp[3]) : "v"(st0[3][2]), "v"(st0[3][3]));
        }
        if (two) {
            u32* pp = (u32*)&pa10;
            asm("v_cvt_pk_bf16_f32 %0, %1, %2" : "=v"(pp[0]) : "v"(st1[0][0]), "v"(st1[0][1]));
            asm("v_cvt_pk_bf16_f32 %0, %1, %2" : "=v"(pp[1]) : "v"(st1[0][2]), "v"(st1[0][3]));
            asm("v_cvt_pk_bf16_f32 %0, %1, %2" : "=v"(pp[2]) : "v"(st1[1][0]), "v"(st1[1][1]));
            asm("v_cvt_pk_bf16_f32 %0, %1, %2" : "=v"(pp[3]) : "v"(st1[1][2]), "v"(st1[1][3]));
            pp = (u32*)&pa11;
            asm("v_cvt_pk_bf16_f32 %0, %1, %2" : "=v"(pp[0]) : "v"(st1[2][0]), "v"(st1[2][1]));
            asm("v_cvt_pk_bf16_f32 %0, %1, %2" : "=v"(pp[1]) : "v"(st1[2][2]), "v"(st1[2][3]));
            asm("v_cvt_pk_bf16_f32 %0, %1, %2" : "=v"(pp[2]) : "v"(st1[3][0]), "v"(st1[3][1]));
            asm("v_cvt_pk_bf16_f32 %0, %1, %2" : "=v"(pp[3]) : "v"(st1[3][2]), "v"(st1[3][3]));
        }

        __syncthreads();   // B: drains V[jr] DMA — Vs ready

        if (jr + 2 < jmax) STAGE_K(jr + 2, p ^ 1)   // flies over PV, drained at A

        // ---- PV, permuted k-axis: B-frag = chunks (tl/4 + 8kk + quad) and ^4
        __builtin_amdgcn_s_setprio(1);
#pragma unroll
        for (int kk = 0; kk < 2; ++kk) {
            short8 a = kk ? pa01 : pa00;
            int c8 = kk * 8 + quad;
#pragma unroll
            for (int ht = 0; ht < 4; ++ht) {
                int rb = (ht * 16 + l15) * 128;
                u64 lo = *(const u64*)&Vs[rb + ((c8 ^ swv) << 2)];
                u64 hi = *(const u64*)&Vs[rb + ((c8 ^ 4 ^ swv) << 2)];
                short8 vb;
                ((u64*)&vb)[0] = lo;
                ((u64*)&vb)[1] = hi;
                ov[ht] = __builtin_amdgcn_mfma_f32_16x16x32_bf16(a, vb, ov[ht], 0, 0, 0);
            }
        }
        if (two) {
#pragma unroll
            for (int kk = 0; kk < 2; ++kk) {
                short8 a = kk ? pa11 : pa10;
                int c8 = 16 + kk * 8 + quad;
#pragma unroll
                for (int ht = 0; ht < 4; ++ht) {
                    int rb = (ht * 16 + l15) * 128;
                    u64 lo = *(const u64*)&Vs[rb + ((c8 ^ swv) << 2)];
                    u64 hi = *(const u64*)&Vs[rb + ((c8 ^ 4 ^ swv) << 2)];
                    short8 vb;
                    ((u64*)&vb)[0] = lo;
                    ((u64*)&vb)[1] = hi;
                    ov[ht] = __builtin_amdgcn_mfma_f32_16x16x32_bf16(a, vb, ov[ht], 0, 0, 0);
                }
            }
        }
        __builtin_amdgcn_s_setprio(0);

        __syncthreads();   // A: drains K[jr+2]; releases Vs and Ks[p]
        p ^= 1;
    }
#undef STAGE_K
#undef STAGE_V

    // ---- deferred l reduction (once per block instead of per round)
    l_run += __shfl_xor(l_run, 16);
    l_run += __shfl_xor(l_run, 32);

    if (qt < 16) {
        // nc==1: this is the row-block's only chunk — normalize and write out.
        float inv = 1.0f / l_run;
        float i0 = __shfl(inv, quad * 4 + 0);
        float i1 = __shfl(inv, quad * 4 + 1);
        float i2 = __shfl(inv, quad * 4 + 2);
        float i3 = __shfl(inv, quad * 4 + 3);
        float* op = out + ((size_t)b * TT + (size_t)qt * 64) * HH;
#pragma unroll
        for (int ht = 0; ht < 4; ++ht)
#pragma unroll
            for (int r = 0; r < 4; ++r) {
                float iv = (r == 0) ? i0 : (r == 1) ? i1 : (r == 2) ? i2 : i3;
                op[(size_t)(wave * 16 + quad * 4 + r) * HH + ht * 16 + l15] =
                    ov[ht][r] * iv;
            }
    } else {
        float* Ob = Opart + ((size_t)((b * 64 + qt) * NCH + c)) * 4096;
#pragma unroll
        for (int ht = 0; ht < 4; ++ht)
#pragma unroll
            for (int r = 0; r < 4; ++r)
                Ob[(size_t)(wave * 16 + quad * 4 + r) * HH + ht * 16 + l15] = ov[ht][r];
        if (quad == 0) {
            size_t mi = (size_t)((b * 64 + qt) * NCH + c) * 64 + wave * 16 + l15;
            Mpart[mi] = m_run;
            Lpart[mi] = l_run;
        }
    }
}

// ---------------------------------------------------------------------------
// Kernel 3: combine partials (exp2 domain), normalize, write fp32 out.
// Array-free form; now only qt>=16 (qt<16 written directly by flash_attn).
// ---------------------------------------------------------------------------
__global__ __launch_bounds__(256) void combine(
    const float* __restrict__ Opart,
    const float* __restrict__ Mpart,
    const float* __restrict__ Lpart,
    float* __restrict__ out)
{
    const int qt = 16 + blockIdx.x;   // 16..63
    const int b  = blockIdx.y;
    const int nc = (qt >> 4) + 1;
    const int t  = threadIdx.x;
    const int row = t >> 2;
    const int seg = t & 3;

    const size_t base = (size_t)(b * 64 + qt) * NCH;

    float M = -1e30f;
    for (int c = 0; c < nc; ++c)
        M = fmaxf(M, Mpart[(base + c) * 64 + row]);

    float L = 0.f;
    f32x4 o[4];
#pragma unroll
    for (int i = 0; i < 4; ++i) o[i] = (f32x4){0.f, 0.f, 0.f, 0.f};
    for (int c = 0; c < nc; ++c) {
        float w = exp2f(Mpart[(base + c) * 64 + row] - M);
        L += w * Lpart[(base + c) * 64 + row];
        const float* Ob = Opart + (base + c) * 4096 + (size_t)row * HH + seg * 16;
#pragma unroll
        for (int i = 0; i < 4; ++i) {
            f32x4 v = *(const f32x4*)(Ob + i * 4);
            o[i] += v * w;
        }
    }
    float invL = 1.0f / L;
    float* op = out + ((size_t)b * TT + qt * 64 + row) * HH + seg * 16;
#pragma unroll
    for (int i = 0; i < 4; ++i)
        *(f32x4*)(op + i * 4) = o[i] * invL;
}

extern "C" void kernel_launch(void* const* d_in, const int* in_sizes, int n_in,
                              void* d_out, int out_size, void* d_ws, size_t ws_size,
                              hipStream_t stream) {
    const float* x  = (const float*)d_in[0];
    const float* Wq = (const float*)d_in[1];
    const float* Wk = (const float*)d_in[2];
    const float* Wv = (const float*)d_in[3];
    float* out = (float*)d_out;

    unsigned short* qkv = (unsigned short*)d_ws;                 // 6.29 MB bf16
    float* Opart = (float*)((char*)d_ws + BF_TOTAL * 2);         // 16.78 MB fp32
    float* Mpart = Opart + (size_t)BB * 64 * NCH * 4096;         // 0.26 MB
    float* Lpart = Mpart + (size_t)BB * 64 * NCH * 64;           // 0.26 MB

    unsigned short* Wt = (unsigned short*)d_out;  // pre-scratch; combine overwrites

    transpose_w<<<dim3(16, 3), 256, 0, stream>>>(Wq, Wk, Wv, Wt);
    qkv_proj<<<dim3(MTOT / 32), 256, 0, stream>>>(x, Wt, qkv);
    flash_attn<<<dim3(64, BB, NCH), 256, 0, stream>>>(qkv, Opart, Mpart, Lpart, out);
    combine<<<dim3(48, BB), 256, 0, stream>>>(Opart, Mpart, Lpart, out);
}

// Round 10
// 151.842 us; speedup vs baseline: 1.0129x; 1.0129x over previous
//
#include <hip/hip_runtime.h>
#include <hip/hip_bf16.h>
#include <math.h>

#define BB 4
#define TT 4096
#define DD 1024
#define HH 64
#define MTOT (BB * TT)   // 16384 rows
#define NCH 4            // key chunks per q row-block (1024 keys each)

typedef short short8 __attribute__((ext_vector_type(8)));
typedef float f32x4  __attribute__((ext_vector_type(4)));
typedef unsigned int u32;
typedef unsigned long long u64;

__device__ __forceinline__ unsigned short f2bf(float f) {
    unsigned u = __builtin_bit_cast(unsigned, f);
    unsigned r = (u + 0x7fffu + ((u >> 16) & 1u)) >> 16;
    return (unsigned short)r;
}

__device__ __forceinline__ unsigned long long pack4(float a, float b, float c, float d) {
    return (unsigned long long)f2bf(a) |
           ((unsigned long long)f2bf(b) << 16) |
           ((unsigned long long)f2bf(c) << 32) |
           ((unsigned long long)f2bf(d) << 48);
}

// async global->LDS DMA, 16B/lane; lds dest = wave-uniform base + lane*16
__device__ __forceinline__ void gl16(const void* g, void* l) {
    __builtin_amdgcn_global_load_lds(
        (const __attribute__((address_space(1))) u32*)g,
        (__attribute__((address_space(3))) u32*)l, 16, 0, 0);
}

// Workspace layout — byte-identical to prior passing rounds
#define QOFF  0
#define KOFF  (MTOT * HH)
#define VOFF  (2 * MTOT * HH)
#define BF_TOTAL (3 * MTOT * HH)

// ---------------------------------------------------------------------------
// Kernel 0: transpose W (1024x64 fp32) -> Wt (64x1024 bf16), 3 matrices.
// (proven, verbatim)
// ---------------------------------------------------------------------------
__global__ __launch_bounds__(256) void transpose_w(
    const float* __restrict__ Wq, const float* __restrict__ Wk,
    const float* __restrict__ Wv, unsigned short* __restrict__ Wt)
{
    const int w = blockIdx.y;
    const float* W = (w == 0) ? Wq : (w == 1) ? Wk : Wv;
    unsigned short* o = Wt + (size_t)w * 64 * 1024;
    const int t  = threadIdx.x;
    const int n4 = t & 15;
    const int k0 = blockIdx.x * 64 + (t >> 4) * 4;

    float v[4][4];
#pragma unroll
    for (int ii = 0; ii < 4; ++ii) {
        float4 r = *(const float4*)&W[(size_t)(k0 + ii) * HH + n4 * 4];
        v[ii][0] = r.x; v[ii][1] = r.y; v[ii][2] = r.z; v[ii][3] = r.w;
    }
#pragma unroll
    for (int cc = 0; cc < 4; ++cc) {
        unsigned long long pk = pack4(v[0][cc], v[1][cc], v[2][cc], v[3][cc]);
        *(unsigned long long*)&o[(size_t)(n4 * 4 + cc) * 1024 + k0] = pk;
    }
}

// ---------------------------------------------------------------------------
// Kernel 1: fused QKV projection (proven DMA K-loop, verbatim R6).
// Q pre-scaled by SC*log2(e); A-fragment pack via v_cvt_pk_bf16_f32.
// ---------------------------------------------------------------------------
__global__ __launch_bounds__(256, 2) void qkv_proj(
    const float* __restrict__ x,
    const unsigned short* __restrict__ Wt,
    unsigned short* __restrict__ qkv)
{
    const int tid   = threadIdx.x;
    const int lane  = tid & 63;
    const int wave  = tid >> 6;      // 0..3
    const int l15   = lane & 15;
    const int quad  = lane >> 4;
    const int m0    = blockIdx.x * 32;
    const int strip = wave & 1;
    const int half  = wave >> 1;

    __shared__ float          Af[2][32 * 64];    // [row][k] fp32, raw (DMA)
    __shared__ unsigned short Bs[2][192 * 64];   // [col][k] bf16, raw (DMA)

    const int ar  = lane >> 4;             // A: row within 4-row instr group
    const int as  = lane & 15;             // A: dest 16B chunk
    const int bc  = lane >> 3;             // B: col within 8-col instr group
    const int bs2 = (lane & 7) ^ bc;       // B: swizzled source chunk

#define STAGEW(it, p)                                                        \
    {                                                                        \
        const int kc_ = (it) * 64;                                           \
        _Pragma("unroll")                                                    \
        for (int jj = 0; jj < 2; ++jj) {                                     \
            int j   = wave * 2 + jj;                                         \
            int row = 4 * j + ar;                                            \
            int sw  = as ^ (row & 15);                                       \
            gl16(x + (size_t)(m0 + row) * DD + kc_ + sw * 4,                 \
                 &Af[p][j * 256]);                                           \
        }                                                                    \
        _Pragma("unroll")                                                    \
        for (int jj = 0; jj < 6; ++jj) {                                     \
            int j    = wave * 6 + jj;                                        \
            int gcol = 8 * j + bc;                                           \
            gl16(Wt + (size_t)gcol * 1024 + kc_ + bs2 * 8,                   \
                 &Bs[p][j * 512]);                                           \
        }                                                                    \
    }

    f32x4 acc[6];
#pragma unroll
    for (int i = 0; i < 6; ++i) acc[i] = (f32x4){0.f, 0.f, 0.f, 0.f};

    STAGEW(0, 0)
    __syncthreads();
    int p = 0;

    for (int it = 0; it < 16; ++it) {
        if (it < 15) STAGEW(it + 1, p ^ 1)

        const int row = strip * 16 + l15;
#pragma unroll
        for (int ks = 0; ks < 2; ++ks) {
            int c0 = ks * 8 + quad * 2;
            float4 a0 = *(const float4*)&Af[p][row * 64 + ((c0)     ^ l15) * 4];
            float4 a1 = *(const float4*)&Af[p][row * 64 + ((c0 + 1) ^ l15) * 4];
            short8 af;
            {
                u32* ap = (u32*)&af;
                asm("v_cvt_pk_bf16_f32 %0, %1, %2" : "=v"(ap[0]) : "v"(a0.x), "v"(a0.y));
                asm("v_cvt_pk_bf16_f32 %0, %1, %2" : "=v"(ap[1]) : "v"(a0.z), "v"(a0.w));
                asm("v_cvt_pk_bf16_f32 %0, %1, %2" : "=v"(ap[2]) : "v"(a1.x), "v"(a1.y));
                asm("v_cvt_pk_bf16_f32 %0, %1, %2" : "=v"(ap[3]) : "v"(a1.z), "v"(a1.w));
            }
            int cb = (ks * 4 + quad) ^ (l15 & 7);
#pragma unroll
            for (int jj = 0; jj < 6; ++jj) {
                int col = (half * 6 + jj) * 16 + l15;
                short8 bfr = *(const short8*)&Bs[p][col * 64 + cb * 8];
                acc[jj] = __builtin_amdgcn_mfma_f32_16x16x32_bf16(af, bfr, acc[jj], 0, 0, 0);
            }
        }
        __syncthreads();
        p ^= 1;
    }
#undef STAGEW

    // ---- epilogue: q (pre-scaled) / k as [b t h] bf16, v transposed [b h t]
    const float QS = 0.125f * 1.44269504088896f;   // scale * log2(e)
    unsigned short* q_bf  = qkv + QOFF;
    unsigned short* k_bf  = qkv + KOFF;
    unsigned short* vt_bf = qkv + VOFF;
#pragma unroll
    for (int jj = 0; jj < 6; ++jj) {
        int g = half * 6 + jj, w = g >> 2, col = (g & 3) * 16 + l15;
#pragma unroll
        for (int r = 0; r < 4; ++r) {
            int m = m0 + strip * 16 + quad * 4 + r;
            float val = acc[jj][r];
            if (w == 0) val *= QS;
            unsigned short bv = f2bf(val);
            if (w == 0)      q_bf[(size_t)m * HH + col] = bv;
            else if (w == 1) k_bf[(size_t)m * HH + col] = bv;
            else {
                int b = m >> 12, t = m & 4095;
                vt_bf[(size_t)b * HH * TT + (size_t)col * TT + t] = bv;
            }
        }
    }
}

// ---------------------------------------------------------------------------
// Kernel 2: causal flash attention — R6 VERBATIM (best measured, 152.6 µs
// total) with exactly ONE graft: the nc==1 fast path.  qt<16 blocks are
// their row-block's only key-chunk, so they normalize in-register and write
// fp32 `out` directly, skipping the Opart/Mpart/Lpart round-trip; combine
// shrinks to qt>=16.  The per-round cross-lane l-reduction is EXACTLY as in
// R6 (R9's deferred-l graft is dropped — suspect +1 µs regression).
// ---------------------------------------------------------------------------
__global__ __launch_bounds__(256, 3) void flash_attn(
    const unsigned short* __restrict__ qkv,
    float* __restrict__ Opart,
    float* __restrict__ Mpart,
    float* __restrict__ Lpart,
    float* __restrict__ out)
{
    const int qt = 63 - blockIdx.x;   // heavy blocks dispatch first
    const int b  = blockIdx.y;
    const int c  = blockIdx.z;
    if (c * 16 > qt) return;
    const int j0   = c * 16;
    const int jmax = min(j0 + 16, qt + 1);

    const int tid  = threadIdx.x;
    const int lane = tid & 63;
    const int wave = tid >> 6;
    const int l15  = lane & 15;
    const int quad = lane >> 4;

    const unsigned short* q_g  = qkv + QOFF + (size_t)b * TT * HH;
    const unsigned short* k_g  = qkv + KOFF + (size_t)b * TT * HH;
    const unsigned short* vt_g = qkv + VOFF + (size_t)b * HH * TT;

    __shared__ unsigned short Ks[2][128 * 64];   // dbuf K, [key][h], src-swizzled
    __shared__ unsigned short Vs[64 * 128];      // single V^T, [h][key], src-swizzled

    // DMA lane decomposition (constant per thread)
    const int kr3 = lane >> 3;        // K: row within 8-row group
    const int kch = lane & 7;         // K: dest 16B chunk
    const int vr2 = lane >> 4;        // V: row within 4-row group
    const int vch = lane & 15;        // V: dest 16B chunk

#define STAGE_K(jr_, p_)                                                      \
    {                                                                         \
        const unsigned short* kp = k_g + (size_t)(jr_) * 64 * HH;             \
        _Pragma("unroll")                                                     \
        for (int i = 0; i < 4; ++i) {                                         \
            int g = wave * 4 + i;                                             \
            gl16(kp + (size_t)(g * 8 + kr3) * HH + (kch ^ kr3) * 8,           \
                 &Ks[p_][g * 512]);                                           \
        }                                                                     \
    }
#define STAGE_V(jr_)                                                          \
    {                                                                         \
        const unsigned short* vp = vt_g + (size_t)(jr_) * 64;                 \
        _Pragma("unroll")                                                     \
        for (int i = 0; i < 4; ++i) {                                         \
            int g = wave * 4 + i;                                             \
            int h = g * 4 + vr2;                                              \
            gl16(vp + (size_t)h * TT + (vch ^ ((h >> 1) & 7)) * 8,            \
                 &Vs[g * 512]);                                               \
        }                                                                     \
    }

    short8 qf[2];
#pragma unroll
    for (int kk = 0; kk < 2; ++kk)
        qf[kk] = *(const short8*)&q_g[(size_t)(qt * 64 + wave * 16 + l15) * HH + kk * 32 + quad * 8];

    f32x4 ov[4];
#pragma unroll
    for (int i = 0; i < 4; ++i) ov[i] = (f32x4){0.f, 0.f, 0.f, 0.f};
    float m_run = -1e30f, l_run = 0.f;

    STAGE_K(j0, 0)
    __syncthreads();   // drains prologue K DMA
    int p = 0;

    const int swv = 2 * ((l15 >> 1) & 7);   // V read-side swizzle (even XOR)

    for (int jr = j0; jr < jmax; jr += 2) {
        const bool two = (jmax - jr) >= 2;

        STAGE_V(jr)                               // covered by QK^T + softmax
        if (jr + 2 < jmax) STAGE_K(jr + 2, p ^ 1) // covered by full round

        // ---- QK^T both tiles (S^T: MFMA rows=key, col(l15)=q)
        f32x4 st0[4], st1[4];
#pragma unroll
        for (int i = 0; i < 4; ++i) {
            st0[i] = (f32x4){0.f, 0.f, 0.f, 0.f};
            st1[i] = (f32x4){0.f, 0.f, 0.f, 0.f};
        }
        __builtin_amdgcn_s_setprio(1);
#pragma unroll
        for (int kk = 0; kk < 2; ++kk)
#pragma unroll
            for (int mt = 0; mt < 4; ++mt) {
                short8 a = *(const short8*)&Ks[p][(mt * 16 + l15) * 64 +
                                                  (((kk * 4 + quad) ^ (l15 & 7)) * 8)];
                st0[mt] = __builtin_amdgcn_mfma_f32_16x16x32_bf16(a, qf[kk], st0[mt], 0, 0, 0);
            }
        if (two) {
#pragma unroll
            for (int kk = 0; kk < 2; ++kk)
#pragma unroll
                for (int mt = 0; mt < 4; ++mt) {
                    short8 a = *(const short8*)&Ks[p][(64 + mt * 16 + l15) * 64 +
                                                      (((kk * 4 + quad) ^ (l15 & 7)) * 8)];
                    st1[mt] = __builtin_amdgcn_mfma_f32_16x16x32_bf16(a, qf[kk], st1[mt], 0, 0, 0);
                }
        }
        __builtin_amdgcn_s_setprio(0);

        // ---- causal mask on the diagonal tile (scores pre-scaled)
        const int qg = wave * 16 + l15;
        if (jr == qt) {
#pragma unroll
            for (int mt = 0; mt < 4; ++mt)
#pragma unroll
                for (int r = 0; r < 4; ++r)
                    if (mt * 16 + quad * 4 + r > qg) st0[mt][r] = -1e30f;
        } else if (two && jr + 1 == qt) {
#pragma unroll
            for (int mt = 0; mt < 4; ++mt)
#pragma unroll
                for (int r = 0; r < 4; ++r)
                    if (mt * 16 + quad * 4 + r > qg) st1[mt][r] = -1e30f;
        }

        // ---- ONE softmax over the whole 128-key round
        float mloc = -1e30f;
#pragma unroll
        for (int mt = 0; mt < 4; ++mt)
#pragma unroll
            for (int r = 0; r < 4; ++r) mloc = fmaxf(mloc, st0[mt][r]);
        if (two) {
#pragma unroll
            for (int mt = 0; mt < 4; ++mt)
#pragma unroll
                for (int r = 0; r < 4; ++r) mloc = fmaxf(mloc, st1[mt][r]);
        }
        mloc = fmaxf(mloc, __shfl_xor(mloc, 16));
        mloc = fmaxf(mloc, __shfl_xor(mloc, 32));

        // exact defer-rescale: when no q-row's max grew, alpha==1 identically
        if (!__all(mloc <= m_run)) {
            const float m_new = fmaxf(m_run, mloc);
            const float alpha = exp2f(m_run - m_new);
            m_run = m_new;
            l_run *= alpha;
            float a0 = __shfl(alpha, quad * 4 + 0);
            float a1 = __shfl(alpha, quad * 4 + 1);
            float a2 = __shfl(alpha, quad * 4 + 2);
            float a3 = __shfl(alpha, quad * 4 + 3);
#pragma unroll
            for (int ht = 0; ht < 4; ++ht) {
                ov[ht][0] *= a0; ov[ht][1] *= a1;
                ov[ht][2] *= a2; ov[ht][3] *= a3;
            }
        }

        float ssum = 0.f;
#pragma unroll
        for (int mt = 0; mt < 4; ++mt)
#pragma unroll
            for (int r = 0; r < 4; ++r) {
                float pv = exp2f(st0[mt][r] - m_run);
                st0[mt][r] = pv; ssum += pv;
            }
        if (two) {
#pragma unroll
            for (int mt = 0; mt < 4; ++mt)
#pragma unroll
                for (int r = 0; r < 4; ++r) {
                    float pv = exp2f(st1[mt][r] - m_run);
                    st1[mt][r] = pv; ssum += pv;
                }
        }
        ssum += __shfl_xor(ssum, 16);
        ssum += __shfl_xor(ssum, 32);
        l_run += ssum;

        // ---- build permuted-k A-fragments in registers (no LDS, no shuffle)
        short8 pa00, pa01, pa10, pa11;
        {
            u32* pp = (u32*)&pa00;
            asm("v_cvt_pk_bf16_f32 %0, %1, %2" : "=v"(pp[0]) : "v"(st0[0][0]), "v"(st0[0][1]));
            asm("v_cvt_pk_bf16_f32 %0, %1, %2" : "=v"(pp[1]) : "v"(st0[0][2]), "v"(st0[0][3]));
            asm("v_cvt_pk_bf16_f32 %0, %1, %2" : "=v"(pp[2]) : "v"(st0[1][0]), "v"(st0[1][1]));
            asm("v_cvt_pk_bf16_f32 %0, %1, %2" : "=v"(pp[3]) : "v"(st0[1][2]), "v"(st0[1][3]));
            pp = (u32*)&pa01;
            asm("v_cvt_pk_bf16_f32 %0, %1, %2" : "=v"(pp[0]) : "v"(st0[2][0]), "v"(st0[2][1]));
            asm("v_cvt_pk_bf16_f32 %0, %1, %2" : "=v"(pp[1]) : "v"(st0[2][2]), "v"(st0[2][3]));
            asm("v_cvt_pk_bf16_f32 %0, %1, %2" : "=v"(pp[2]) : "v"(st0[3][0]), "v"(st0[3][1]));
            asm("v_cvt_pk_bf16_f32 %0, %1, %2" : "=v"(pp[3]) : "v"(st0[3][2]), "v"(st0[3][3]));
        }
        if (two) {
            u32* pp = (u32*)&pa10;
            asm("v_cvt_pk_bf16_f32 %0, %1, %2" : "=v"(pp[0]) : "v"(st1[0][0]), "v"(st1[0][1]));
            asm("v_cvt_pk_bf16_f32 %0, %1, %2" : "=v"(pp[1]) : "v"(st1[0][2]), "v"(st1[0][3]));
            asm("v_cvt_pk_bf16_f32 %0, %1, %2" : "=v"(pp[2]) : "v"(st1[1][0]), "v"(st1[1][1]));
            asm("v_cvt_pk_bf16_f32 %0, %1, %2" : "=v"(pp[3]) : "v"(st1[1][2]), "v"(st1[1][3]));
            pp = (u32*)&pa11;
            asm("v_cvt_pk_bf16_f32 %0, %1, %2" : "=v"(pp[0]) : "v"(st1[2][0]), "v"(st1[2][1]));
            asm("v_cvt_pk_bf16_f32 %0, %1, %2" : "=v"(pp[1]) : "v"(st1[2][2]), "v"(st1[2][3]));
            asm("v_cvt_pk_bf16_f32 %0, %1, %2" : "=v"(pp[2]) : "v"(st1[3][0]), "v"(st1[3][1]));
            asm("v_cvt_pk_bf16_f32 %0, %1, %2" : "=v"(pp[3]) : "v"(st1[3][2]), "v"(st1[3][3]));
        }

        __syncthreads();   // B: drains V[jr] (+K[jr+2]) DMA — Vs ready

        // ---- PV, permuted k-axis: B-frag = chunks (tl/4 + 8kk + quad) and ^4
        __builtin_amdgcn_s_setprio(1);
#pragma unroll
        for (int kk = 0; kk < 2; ++kk) {
            short8 a = kk ? pa01 : pa00;
            int c8 = kk * 8 + quad;
#pragma unroll
            for (int ht = 0; ht < 4; ++ht) {
                int rb = (ht * 16 + l15) * 128;
                u64 lo = *(const u64*)&Vs[rb + ((c8 ^ swv) << 2)];
                u64 hi = *(const u64*)&Vs[rb + ((c8 ^ 4 ^ swv) << 2)];
                short8 vb;
                ((u64*)&vb)[0] = lo;
                ((u64*)&vb)[1] = hi;
                ov[ht] = __builtin_amdgcn_mfma_f32_16x16x32_bf16(a, vb, ov[ht], 0, 0, 0);
            }
        }
        if (two) {
#pragma unroll
            for (int kk = 0; kk < 2; ++kk) {
                short8 a = kk ? pa11 : pa10;
                int c8 = 16 + kk * 8 + quad;
#pragma unroll
                for (int ht = 0; ht < 4; ++ht) {
                    int rb = (ht * 16 + l15) * 128;
                    u64 lo = *(const u64*)&Vs[rb + ((c8 ^ swv) << 2)];
                    u64 hi = *(const u64*)&Vs[rb + ((c8 ^ 4 ^ swv) << 2)];
                    short8 vb;
                    ((u64*)&vb)[0] = lo;
                    ((u64*)&vb)[1] = hi;
                    ov[ht] = __builtin_amdgcn_mfma_f32_16x16x32_bf16(a, vb, ov[ht], 0, 0, 0);
                }
            }
        }
        __builtin_amdgcn_s_setprio(0);

        __syncthreads();   // A: release Vs and Ks[p] for next round's DMA
        p ^= 1;
    }
#undef STAGE_K
#undef STAGE_V

    if (qt < 16) {
        // nc==1: this is the row-block's only chunk — normalize, write out.
        float inv = 1.0f / l_run;
        float i0 = __shfl(inv, quad * 4 + 0);
        float i1 = __shfl(inv, quad * 4 + 1);
        float i2 = __shfl(inv, quad * 4 + 2);
        float i3 = __shfl(inv, quad * 4 + 3);
        float* op = out + ((size_t)b * TT + (size_t)qt * 64) * HH;
#pragma unroll
        for (int ht = 0; ht < 4; ++ht) {
            op[(size_t)(wave * 16 + quad * 4 + 0) * HH + ht * 16 + l15] = ov[ht][0] * i0;
            op[(size_t)(wave * 16 + quad * 4 + 1) * HH + ht * 16 + l15] = ov[ht][1] * i1;
            op[(size_t)(wave * 16 + quad * 4 + 2) * HH + ht * 16 + l15] = ov[ht][2] * i2;
            op[(size_t)(wave * 16 + quad * 4 + 3) * HH + ht * 16 + l15] = ov[ht][3] * i3;
        }
    } else {
        float* Ob = Opart + ((size_t)((b * 64 + qt) * NCH + c)) * 4096;
#pragma unroll
        for (int ht = 0; ht < 4; ++ht)
#pragma unroll
            for (int r = 0; r < 4; ++r)
                Ob[(size_t)(wave * 16 + quad * 4 + r) * HH + ht * 16 + l15] = ov[ht][r];
        if (quad == 0) {
            size_t mi = (size_t)((b * 64 + qt) * NCH + c) * 64 + wave * 16 + l15;
            Mpart[mi] = m_run;
            Lpart[mi] = l_run;
        }
    }
}

// ---------------------------------------------------------------------------
// Kernel 3: combine partials (exp2 domain), normalize, write fp32 out.
// Array-free form; only qt>=16 (qt<16 written directly by flash_attn).
// ---------------------------------------------------------------------------
__global__ __launch_bounds__(256) void combine(
    const float* __restrict__ Opart,
    const float* __restrict__ Mpart,
    const float* __restrict__ Lpart,
    float* __restrict__ out)
{
    const int qt = 16 + blockIdx.x;   // 16..63
    const int b  = blockIdx.y;
    const int nc = (qt >> 4) + 1;
    const int t  = threadIdx.x;
    const int row = t >> 2;
    const int seg = t & 3;

    const size_t base = (size_t)(b * 64 + qt) * NCH;

    float M = -1e30f;
    for (int c = 0; c < nc; ++c)
        M = fmaxf(M, Mpart[(base + c) * 64 + row]);

    float L = 0.f;
    f32x4 o[4];
#pragma unroll
    for (int i = 0; i < 4; ++i) o[i] = (f32x4){0.f, 0.f, 0.f, 0.f};
    for (int c = 0; c < nc; ++c) {
        float w = exp2f(Mpart[(base + c) * 64 + row] - M);
        L += w * Lpart[(base + c) * 64 + row];
        const float* Ob = Opart + (base + c) * 4096 + (size_t)row * HH + seg * 16;
#pragma unroll
        for (int i = 0; i < 4; ++i) {
            f32x4 v = *(const f32x4*)(Ob + i * 4);
            o[i] += v * w;
        }
    }
    float invL = 1.0f / L;
    float* op = out + ((size_t)b * TT + qt * 64 + row) * HH + seg * 16;
#pragma unroll
    for (int i = 0; i < 4; ++i)
        *(f32x4*)(op + i * 4) = o[i] * invL;
}

extern "C" void kernel_launch(void* const* d_in, const int* in_sizes, int n_in,
                              void* d_out, int out_size, void* d_ws, size_t ws_size,
                              hipStream_t stream) {
    const float* x  = (const float*)d_in[0];
    const float* Wq = (const float*)d_in[1];
    const float* Wk = (const float*)d_in[2];
    const float* Wv = (const float*)d_in[3];
    float* out = (float*)d_out;

    unsigned short* qkv = (unsigned short*)d_ws;                 // 6.29 MB bf16
    float* Opart = (float*)((char*)d_ws + BF_TOTAL * 2);         // 16.78 MB fp32
    float* Mpart = Opart + (size_t)BB * 64 * NCH * 4096;         // 0.26 MB
    float* Lpart = Mpart + (size_t)BB * 64 * NCH * 64;           // 0.26 MB

    unsigned short* Wt = (unsigned short*)d_out;  // pre-scratch; combine overwrites

    transpose_w<<<dim3(16, 3), 256, 0, stream>>>(Wq, Wk, Wv, Wt);
    qkv_proj<<<dim3(MTOT / 32), 256, 0, stream>>>(x, Wt, qkv);
    flash_attn<<<dim3(64, BB, NCH), 256, 0, stream>>>(qkv, Opart, Mpart, Lpart, out);
    combine<<<dim3(48, BB), 256, 0, stream>>>(Opart, Mpart, Lpart, out);
}